// Round 4
// baseline (92.144 us; speedup 1.0000x reference)
//
#include <hip/hip_runtime.h>
#include <math.h>

#define V     4096
#define NB    8
#define TPB   256
#define NRCH  32              // ref chunks
#define RCH   (V / NRCH)      // 128 refs per chunk
#define Q     8               // queries per thread
#define QPB   (TPB * Q)       // 2048 queries per block
#define QCH   (V / QPB)       // 2 query chunks

// ws layout: partial[16][NRCH][V] floats (8 MB), then best[8] ints.
// No init required anywhere: phase2 uses signed-int atomicMax, and the
// harness 0xAA poison is a negative int == -inf for that ordering.

// Phase 1: block = (rchunk, qchunk, dirn). Stages its 128-point ref chunk in
// LDS packed as (-2x,-2y,-2z,|r|^2): each (query,ref) pair = 3 fmaf + 1 fminf.
// Each thread owns Q=8 queries; one broadcast ds_read_b128 per ref point is
// amortized over 32 VALU insts. Epilogue: clamp(q2+m,0) -> PLAIN coalesced
// stores (replaces 2.1M-atomic tail of the previous version).
__global__ __launch_bounds__(TPB) void hausdorff_min(
    const float* __restrict__ x, const float* __restrict__ y,
    float* __restrict__ partial)
{
    __shared__ float  sraw[3 * RCH];   // 1.5 KB raw staging
    __shared__ float4 sref[RCH];       // 2 KB packed (-2x,-2y,-2z,r2)

    const int rc   = blockIdx.x;
    const int qch  = blockIdx.y;
    const int dirn = blockIdx.z;       // n = dirn&7, dir = dirn>>3
    const int n    = dirn & (NB - 1);
    const int dir  = dirn >> 3;
    const int t    = threadIdx.x;

    const float* qb = (dir ? y : x) + (size_t)n * (3 * V);
    const float* rb = (dir ? x : y) + (size_t)n * (3 * V) + rc * (3 * RCH);

    // Stage 384 floats, coalesced.
    for (int i = t; i < 3 * RCH; i += TPB)
        sraw[i] = rb[i];

    // Query points (independent of LDS staging -> overlaps).
    float qx[Q], qy[Q], qz[Q], q2[Q], m[Q];
    #pragma unroll
    for (int k = 0; k < Q; ++k) {
        int qi = qch * QPB + k * TPB + t;
        qx[k] = qb[3 * qi]; qy[k] = qb[3 * qi + 1]; qz[k] = qb[3 * qi + 2];
        q2[k] = fmaf(qx[k], qx[k], fmaf(qy[k], qy[k], qz[k] * qz[k]));
        m[k]  = 3.0e38f;
    }
    __syncthreads();

    // Pack pass: stride-3 reads, gcd(3,32)=1 -> conflict-free.
    if (t < RCH) {
        float rx = sraw[3 * t], ry = sraw[3 * t + 1], rz = sraw[3 * t + 2];
        sref[t] = make_float4(-2.0f * rx, -2.0f * ry, -2.0f * rz,
                              fmaf(rx, rx, fmaf(ry, ry, rz * rz)));
    }
    __syncthreads();

    // Main loop: 128 iters x (1 broadcast ds_read_b128 + 32 VALU).
    #pragma unroll 8
    for (int j = 0; j < RCH; ++j) {
        float4 p = sref[j];
        #pragma unroll
        for (int k = 0; k < Q; ++k) {
            float d = fmaf(qx[k], p.x, fmaf(qy[k], p.y, fmaf(qz[k], p.z, p.w)));
            m[k] = fminf(m[k], d);
        }
    }

    // clamp commutes with the later min over rc. Coalesced dword stores.
    float* out = partial + ((size_t)dirn * NRCH + rc) * V + qch * QPB + t;
    #pragma unroll
    for (int k = 0; k < Q; ++k)
        out[k * TPB] = fmaxf(q2[k] + m[k], 0.0f);
}

// Phase 2: 512 blocks x 128 threads. Thread (dirn,q): min over the 32 rc
// partials (coalesced, L2-resident, fully unrolled -> 32 loads in flight),
// then wave max-reduce and ONE int-bit atomicMax per wave into best[n].
// Values are nonneg floats -> int ordering == float ordering; 0xAA poison
// is negative -> acts as -inf, so best[] needs no initialization.
__global__ __launch_bounds__(128) void hausdorff_combine(
    const float* __restrict__ partial, int* __restrict__ best)
{
    const int dirn = blockIdx.y;
    const int n    = dirn & (NB - 1);
    const int q    = blockIdx.x * 128 + threadIdx.x;
    const float* base = partial + (size_t)dirn * NRCH * V + q;
    float mn = base[0];
    #pragma unroll
    for (int rc = 1; rc < NRCH; ++rc)
        mn = fminf(mn, base[(size_t)rc * V]);
    #pragma unroll
    for (int off = 32; off > 0; off >>= 1)
        mn = fmaxf(mn, __shfl_xor(mn, off));
    if ((threadIdx.x & 63) == 0)
        atomicMax(&best[n], __float_as_int(mn));
}

// Phase 3: scalar finalize, plain store (no d_out init needed).
__global__ void hausdorff_final(const int* __restrict__ best,
                                float* __restrict__ out)
{
    if (threadIdx.x == 0) {
        float s = 0.0f;
        #pragma unroll
        for (int n = 0; n < NB; ++n)
            s += sqrtf(__int_as_float(best[n]));
        out[0] = s * (1.0f / NB);
    }
}

extern "C" void kernel_launch(void* const* d_in, const int* in_sizes, int n_in,
                              void* d_out, int out_size, void* d_ws, size_t ws_size,
                              hipStream_t stream)
{
    const float* x = (const float*)d_in[0];
    const float* y = (const float*)d_in[1];
    float* partial = (float*)d_ws;                       // 16*32*4096 f32 = 8 MB
    int*   best    = (int*)((char*)d_ws + (size_t)2 * NB * NRCH * V * sizeof(float));

    hausdorff_min    <<<dim3(NRCH, QCH, 2 * NB), TPB, 0, stream>>>(x, y, partial);
    hausdorff_combine<<<dim3(V / 128, 2 * NB),   128, 0, stream>>>(partial, best);
    hausdorff_final  <<<1, 64, 0, stream>>>(best, (float*)d_out);
}

// Round 5
// 81.080 us; speedup vs baseline: 1.1365x; 1.1365x over previous
//
#include <hip/hip_runtime.h>
#include <math.h>

#define V     4096
#define NB    8
#define TPB   256
#define NRCH  32               // ref chunks per direction
#define PPRC  64               // ref PAIRS per chunk (128 refs)
#define Q     8                // queries per thread
#define QPB   (TPB * Q)        // 2048 queries per block
#define QCH   (V / QPB)        // 2 query chunks
#define NPAIR (2 * NB * (V/2)) // 32768 total ref pairs

typedef float v2f __attribute__((ext_vector_type(2)));

// ws layout: pk[32768][2] float4 (1 MB) | cells[16*4096] uint (256 KB)

// Pre-kernel: pack ref pairs as (-2x,-2y,-2z,r^2) interleaved for v_pk_fma_f32,
// and initialize the atomic-min cells (saves a memset dispatch).
// pair g: dir = g>>14 (refs are y for dir0, x for dir1), cloud-local offset
// (g & 16383)*6 floats = two consecutive points.
__global__ __launch_bounds__(TPB) void hausdorff_pack(
    const float* __restrict__ x, const float* __restrict__ y,
    float4* __restrict__ pk, unsigned int* __restrict__ cells)
{
    const int g = blockIdx.x * TPB + threadIdx.x;     // 0..32767
    const int dir = g >> 14;
    const float* c = (dir ? x : y) + (size_t)(g & 16383) * 6;
    float ax = c[0], ay = c[1], az = c[2];
    float bx = c[3], by = c[4], bz = c[5];
    pk[2 * g]     = make_float4(-2.f * ax, -2.f * bx, -2.f * ay, -2.f * by);
    pk[2 * g + 1] = make_float4(-2.f * az, -2.f * bz,
                                fmaf(ax, ax, fmaf(ay, ay, az * az)),
                                fmaf(bx, bx, fmaf(by, by, bz * bz)));
    cells[2 * g]     = 0x7f7f7f7fu;   // 3.39e38f, > any d^2 here
    cells[2 * g + 1] = 0x7f7f7f7fu;
}

// Main: block = (rchunk, qchunk, dirn). No LDS, no syncs. Refs read at a
// WAVE-UNIFORM index from the packed array (scalarizable / L1-broadcast).
// Inner: per ref-pair per query = 3 pk_fma + 2 v_min (5 insts / 2 dists).
// Epilogue: clamp(q2+min,0) -> uint-bit atomicMin (exact for nonneg floats,
// order-independent, measured ~free in R3).
__global__ __launch_bounds__(TPB) void hausdorff_min(
    const float* __restrict__ x, const float* __restrict__ y,
    const float4* __restrict__ pk, unsigned int* __restrict__ cells)
{
    const int rc = blockIdx.x, qch = blockIdx.y, dirn = blockIdx.z;
    const int n = dirn & (NB - 1), dir = dirn >> 3;
    const int t = threadIdx.x;

    const float* qb = (dir ? y : x) + (size_t)n * (3 * V);
    const float4* pr = pk + ((size_t)dirn * (V / 2) + rc * PPRC) * 2;

    float qxv[Q], qyv[Q], qzv[Q], q2[Q], ma[Q], mb[Q];
    #pragma unroll
    for (int k = 0; k < Q; ++k) {
        int qi = qch * QPB + k * TPB + t;
        float a = qb[3 * qi], b = qb[3 * qi + 1], c = qb[3 * qi + 2];
        qxv[k] = a; qyv[k] = b; qzv[k] = c;
        q2[k] = fmaf(a, a, fmaf(b, b, c * c));
        ma[k] = 3.0e38f; mb[k] = 3.0e38f;
    }

    #pragma unroll 4
    for (int j = 0; j < PPRC; ++j) {
        float4 p0 = pr[2 * j], p1 = pr[2 * j + 1];
        v2f mx = {p0.x, p0.y}, my = {p0.z, p0.w};
        v2f mz = {p1.x, p1.y}, r2 = {p1.z, p1.w};
        #pragma unroll
        for (int k = 0; k < Q; ++k) {
            v2f d = __builtin_elementwise_fma((v2f){qzv[k], qzv[k]}, mz, r2);
            d = __builtin_elementwise_fma((v2f){qyv[k], qyv[k]}, my, d);
            d = __builtin_elementwise_fma((v2f){qxv[k], qxv[k]}, mx, d);
            ma[k] = fminf(ma[k], d.x);
            mb[k] = fminf(mb[k], d.y);
        }
    }

    unsigned int* cell = cells + (size_t)dirn * V + qch * QPB + t;
    #pragma unroll
    for (int k = 0; k < Q; ++k) {
        float mn = fminf(ma[k], mb[k]);
        atomicMin(cell + k * TPB, __float_as_uint(fmaxf(q2[k] + mn, 0.f)));
    }
}

// Final: one block, 16 waves; wave w max-reduces row dirn=w (4096 cells,
// uint4 loads), then lanes 0..7 of wave 0 combine dir pairs, sqrt, sum,
// plain store (no d_out init needed).
__global__ __launch_bounds__(1024) void hausdorff_final(
    const unsigned int* __restrict__ cells, float* __restrict__ out)
{
    __shared__ float sm[16];
    const int t = threadIdx.x, w = t >> 6, lane = t & 63;
    const uint4* row = (const uint4*)(cells + (size_t)w * V);
    float v = 0.f;
    #pragma unroll
    for (int i = 0; i < 16; ++i) {
        uint4 u = row[lane + 64 * i];
        v = fmaxf(v, fmaxf(fmaxf(__uint_as_float(u.x), __uint_as_float(u.y)),
                           fmaxf(__uint_as_float(u.z), __uint_as_float(u.w))));
    }
    #pragma unroll
    for (int off = 32; off; off >>= 1)
        v = fmaxf(v, __shfl_xor(v, off));
    if (lane == 0) sm[w] = v;
    __syncthreads();
    if (t < 8) {
        float s = sqrtf(fmaxf(sm[t], sm[t + 8]));   // max over directions
        s += __shfl_xor(s, 4);
        s += __shfl_xor(s, 2);
        s += __shfl_xor(s, 1);
        if (t == 0) out[0] = s * (1.0f / NB);
    }
}

extern "C" void kernel_launch(void* const* d_in, const int* in_sizes, int n_in,
                              void* d_out, int out_size, void* d_ws, size_t ws_size,
                              hipStream_t stream)
{
    const float* x = (const float*)d_in[0];
    const float* y = (const float*)d_in[1];
    float4* pk = (float4*)d_ws;                                   // 1 MB
    unsigned int* cells =
        (unsigned int*)((char*)d_ws + (size_t)2 * NPAIR * sizeof(float4));

    hausdorff_pack <<<NPAIR / TPB, TPB, 0, stream>>>(x, y, pk, cells);
    hausdorff_min  <<<dim3(NRCH, QCH, 2 * NB), TPB, 0, stream>>>(x, y, pk, cells);
    hausdorff_final<<<1, 1024, 0, stream>>>(cells, (float*)d_out);
}